// Round 1
// baseline (21872.194 us; speedup 1.0000x reference)
//
#include <hip/hip_runtime.h>
#include <math.h>

// OSPNet: pool(2x2) -> 1x1 conv -> spatial covariance -> eigh -> log(clamp(w,1e-4))
//         -> V diag(logw) V^T -> triu flatten (*sqrt2 offdiag) -> MLP -> [32,3]
//
// Eigh strategy: per-matrix two-sided parallel Jacobi on packed lower triangle in LDS
// (128.5 KB; A + eigenvectors cannot both fit in 160 KB). Rotations are logged to
// global memory and replayed in REVERSE on diag(log lambda) to form J logL J^T
// without ever materializing V.

#define SWEEPS 10
#define NROT_PER_MAT (SWEEPS * 255 * 128)

// ---- workspace layout (bytes) ----
// regionA [0, 83558400): P (pool out, 79691776) + mean (at 79691776, 32768); later
//                        overwritten by rotlog (83558400) once P/mean are dead.
// f/flat  [83558400, 93519872): f (9961472); later flat (4210688) overlays it.
// cov     [93519872, 101908480): cov (8388608); later partial (1048576) + h (32768).
// rmax    [101908480, 102234880): per-round max|s| (32*2550 floats).
#define P_OFF     0
#define MEAN_OFF  79691776
#define RLOG_OFF  0
#define F_OFF     83558400
#define FLAT_OFF  83558400
#define COV_OFF   93519872
#define PART_OFF  93519872
#define H_OFF     94568448
#define RMAX_OFF  101908480
#define WS_REQUIRED 102234880

// ---------------- k1: 2x2 average pool:  x[32][2048][34][34] -> P[32][2048][304] (289 valid)
__global__ __launch_bounds__(256) void k_pool(const float* __restrict__ x, float* __restrict__ P) {
    int c = blockIdx.x, b = blockIdx.y;
    const float* xs = x + (size_t)(b * 2048 + c) * 1156;
    float* ps = P + (size_t)(b * 2048 + c) * 304;
    for (int n = threadIdx.x; n < 289; n += 256) {
        int i = n / 17, j = n % 17;
        int base = (2 * i) * 34 + 2 * j;
        ps[n] = 0.25f * (xs[base] + xs[base + 1] + xs[base + 34] + xs[base + 35]);
    }
}

// ---------------- k2: channel reduction GEMM: f[b][d][n] = sum_c Wr[d][c] * P[b][c][n]
__global__ __launch_bounds__(256) void k_gemm_red(const float* __restrict__ P,
                                                  const float* __restrict__ Wr,
                                                  float* __restrict__ f) {
    __shared__ float Wt[32][33];
    __shared__ float Pt[32][64];
    int nt = blockIdx.x, dt = blockIdx.y, b = blockIdx.z;
    int n0 = nt * 64, d0 = dt * 32;
    int tid = threadIdx.x;
    int ty = tid >> 4, tx = tid & 15;
    float acc[2][4] = {};
    for (int c0 = 0; c0 < 2048; c0 += 32) {
        __syncthreads();
        for (int idx = tid; idx < 32 * 32; idx += 256) {
            int r = idx >> 5, cc = idx & 31;
            Wt[r][cc] = Wr[(size_t)(d0 + r) * 2048 + c0 + cc];
        }
        for (int idx = tid; idx < 32 * 64; idx += 256) {
            int r = idx >> 6, cc = idx & 63;
            int n = n0 + cc;
            Pt[r][cc] = (n < 289) ? P[(size_t)(b * 2048 + c0 + r) * 304 + n] : 0.0f;
        }
        __syncthreads();
#pragma unroll
        for (int kk = 0; kk < 32; ++kk) {
            float a0 = Wt[ty * 2 + 0][kk], a1 = Wt[ty * 2 + 1][kk];
            float p0 = Pt[kk][tx * 4 + 0], p1 = Pt[kk][tx * 4 + 1];
            float p2 = Pt[kk][tx * 4 + 2], p3 = Pt[kk][tx * 4 + 3];
            acc[0][0] += a0 * p0; acc[0][1] += a0 * p1; acc[0][2] += a0 * p2; acc[0][3] += a0 * p3;
            acc[1][0] += a1 * p0; acc[1][1] += a1 * p1; acc[1][2] += a1 * p2; acc[1][3] += a1 * p3;
        }
    }
    for (int ii = 0; ii < 2; ++ii)
        for (int jj = 0; jj < 4; ++jj) {
            int d = d0 + ty * 2 + ii, n = n0 + tx * 4 + jj;
            if (n < 289) f[(size_t)(b * 256 + d) * 304 + n] = acc[ii][jj];
        }
}

// ---------------- k3a: per-(b,d) spatial mean over 289 positions (fp64 accumulate)
__global__ __launch_bounds__(256) void k_mean(const float* __restrict__ f, float* __restrict__ mean) {
    int row = blockIdx.x * 4 + (threadIdx.x >> 6);  // b*256+d
    int lane = threadIdx.x & 63;
    const float* fr = f + (size_t)row * 304;
    double s = 0.0;
    for (int n = lane; n < 289; n += 64) s += (double)fr[n];
    for (int off = 32; off; off >>= 1) s += __shfl_down(s, off);
    if (lane == 0) mean[row] = (float)(s / 289.0);
}

// ---------------- k3b: covariance, fp64 accumulate: cov[b][i][j] (lower half valid)
__global__ __launch_bounds__(256) void k_cov(const float* __restrict__ f,
                                             const float* __restrict__ mean,
                                             float* __restrict__ cov) {
    __shared__ float Fi[32][33];
    __shared__ float Fj[32][33];
    int b = blockIdx.x, tp = blockIdx.y;
    int ti = (int)((sqrtf(8.0f * tp + 1.0f) - 1.0f) * 0.5f);
    while (ti * (ti + 1) / 2 > tp) --ti;
    while ((ti + 1) * (ti + 2) / 2 <= tp) ++ti;
    int tj = tp - ti * (ti + 1) / 2;
    int tid = threadIdx.x;
    int tyy = tid >> 4, txx = tid & 15;
    bool diag = (ti == tj);
    double acc[2][2] = {};
    for (int nc = 0; nc < 289; nc += 32) {
        __syncthreads();
        for (int idx = tid; idx < 32 * 32; idx += 256) {
            int r = idx >> 5, k = idx & 31;
            int n = nc + k;
            int d1 = ti * 32 + r;
            Fi[r][k] = (n < 289) ? f[(size_t)(b * 256 + d1) * 304 + n] - mean[b * 256 + d1] : 0.0f;
            if (!diag) {
                int d2 = tj * 32 + r;
                Fj[r][k] = (n < 289) ? f[(size_t)(b * 256 + d2) * 304 + n] - mean[b * 256 + d2] : 0.0f;
            }
        }
        __syncthreads();
        const float(*FJ)[33] = diag ? Fi : Fj;
#pragma unroll 8
        for (int kk = 0; kk < 32; ++kk) {
            float a0 = Fi[tyy * 2 + 0][kk], a1 = Fi[tyy * 2 + 1][kk];
            float c0 = FJ[txx * 2 + 0][kk], c1 = FJ[txx * 2 + 1][kk];
            acc[0][0] += (double)a0 * c0; acc[0][1] += (double)a0 * c1;
            acc[1][0] += (double)a1 * c0; acc[1][1] += (double)a1 * c1;
        }
    }
    for (int ii = 0; ii < 2; ++ii)
        for (int jj = 0; jj < 2; ++jj) {
            int i = ti * 32 + tyy * 2 + ii, j = tj * 32 + txx * 2 + jj;
            cov[((size_t)b << 16) + i * 256 + j] = (float)(acc[ii][jj] * (1.0 / 288.0));
        }
}

// ---------------- k4: batched Jacobi eigh + rotation-replay logm
__device__ __forceinline__ void pair_rt(int r, int t, int& p, int& q) {
    // round-robin tournament, closed form: round r in [0,255), slot t in [0,128)
    if (t == 0) { p = 0; q = 1 + r; return; }
    int u = r + t; if (u >= 255) u -= 255;
    int v = r - t; if (v < 0) v += 255;
    p = 1 + u; q = 1 + v;
    if (p > q) { int w = p; p = q; q = w; }
}
__device__ __forceinline__ int pk(int i, int j) {  // packed lower index, i != j ok
    return (i > j) ? (i * (i + 1) / 2 + j) : (j * (j + 1) / 2 + i);
}

__global__ __launch_bounds__(1024) void k_jacobi(const float* __restrict__ cov,
                                                 float2* __restrict__ rotlog,
                                                 float* __restrict__ grmax,
                                                 float* __restrict__ flat) {
    extern __shared__ float sm[];
    float* A = sm;                          // 32896
    float* c_arr = A + 32896;               // 128
    float* s_arr = c_arr + 128;             // 128
    int* p_arr = (int*)(s_arr + 128);       // 128
    int* q_arr = p_arr + 128;               // 128
    float* lam = (float*)(q_arr + 128);     // 256
    float* wmax = lam + 256;                // 2
    unsigned short* dtab = (unsigned short*)(wmax + 2);  // 8128 entries

    int b = blockIdx.x;
    int tid = threadIdx.x;
    const float* covb = cov + ((size_t)b << 16);
    float2* rlog = rotlog + (size_t)b * NROT_PER_MAT;
    float* rmax = grmax + (size_t)b * (SWEEPS * 255);

    // load packed lower triangle; precompute block-pair decode table
    for (int e = tid; e < 32896; e += 1024) {
        int r = (int)((sqrtf(8.0f * e + 1.0f) - 1.0f) * 0.5f);
        while (r * (r + 1) / 2 > e) --r;
        while ((r + 1) * (r + 2) / 2 <= e) ++r;
        int c = e - r * (r + 1) / 2;
        A[e] = covb[r * 256 + c];
    }
    for (int k = tid; k < 8128; k += 1024) {
        int bb = (int)((sqrtf(8.0f * k + 1.0f) + 1.0f) * 0.5f);
        while (bb * (bb - 1) / 2 > k) --bb;
        while ((bb + 1) * bb / 2 <= k) ++bb;
        int aa = k - bb * (bb - 1) / 2;
        dtab[k] = (unsigned short)(aa | (bb << 8));
    }
    __syncthreads();

    // ---- forward: A -> Lambda, logging rotations
    for (int sw = 0; sw < SWEEPS; ++sw) {
        for (int r = 0; r < 255; ++r) {
            if (tid < 128) {
                int p, q; pair_rt(r, tid, p, q);
                int ipp = p * (p + 1) / 2 + p;
                int iqq = q * (q + 1) / 2 + q;
                int ipq = q * (q + 1) / 2 + p;
                float app = A[ipp], aqq = A[iqq], apq = A[ipq];
                double cd = 1.0, sd = 0.0;
                if (apq != 0.0f) {
                    double tau = ((double)aqq - (double)app) / (2.0 * (double)apq);
                    double tt = 1.0 / (fabs(tau) + sqrt(1.0 + tau * tau));
                    if (tau < 0.0) tt = -tt;
                    cd = 1.0 / sqrt(1.0 + tt * tt);
                    sd = tt * cd;
                    A[ipp] = (float)((double)app - tt * (double)apq);
                    A[iqq] = (float)((double)aqq + tt * (double)apq);
                    A[ipq] = 0.0f;
                }
                c_arr[tid] = (float)cd; s_arr[tid] = (float)sd;
                p_arr[tid] = p; q_arr[tid] = q;
                rlog[(size_t)(sw * 255 + r) * 128 + tid] = make_float2((float)cd, (float)sd);
                float as = fabsf((float)sd);
#pragma unroll
                for (int off = 32; off; off >>= 1) as = fmaxf(as, __shfl_down(as, off));
                if ((tid & 63) == 0) wmax[tid >> 6] = as;
            }
            __syncthreads();
            if (tid == 0) rmax[sw * 255 + r] = fmaxf(wmax[0], wmax[1]);
            for (int k = tid; k < 8128; k += 1024) {
                unsigned short ab = dtab[k];
                int aa = ab & 255, bb = ab >> 8;
                int p1 = p_arr[aa], q1 = q_arr[aa];
                int p2 = p_arr[bb], q2 = q_arr[bb];
                float ca = c_arr[aa], sa = s_arr[aa];
                float cb = c_arr[bb], sb = s_arr[bb];
                int i00 = pk(p1, p2), i01 = pk(p1, q2), i10 = pk(q1, p2), i11 = pk(q1, q2);
                float x00 = A[i00], x01 = A[i01], x10 = A[i10], x11 = A[i11];
                float y00 = ca * x00 - sa * x10, y10 = sa * x00 + ca * x10;
                float y01 = ca * x01 - sa * x11, y11 = sa * x01 + ca * x11;
                A[i00] = cb * y00 - sb * y01; A[i01] = sb * y00 + cb * y01;
                A[i10] = cb * y10 - sb * y11; A[i11] = sb * y10 + cb * y11;
            }
            __syncthreads();
        }
    }

    // ---- eigenvalues -> clamped log on the diagonal, zero elsewhere
    if (tid < 256) lam[tid] = logf(fmaxf(A[tid * (tid + 1) / 2 + tid], 1e-4f));
    __syncthreads();
    for (int e = tid; e < 32896; e += 1024) A[e] = 0.0f;
    __syncthreads();
    if (tid < 256) A[tid * (tid + 1) / 2 + tid] = lam[tid];
    __syncthreads();

    // ---- replay rotations in reverse: M <- J M J^T  => M = J logL J^T = log(cov)
    for (int sw = SWEEPS - 1; sw >= 0; --sw) {
        for (int r = 254; r >= 0; --r) {
            float rm = rmax[sw * 255 + r];
            if (rm < 1e-9f) continue;  // converged round: J_r ~ I (uniform branch)
            if (tid < 128) {
                int p, q; pair_rt(r, tid, p, q);
                float2 cs = rlog[(size_t)(sw * 255 + r) * 128 + tid];
                float c = cs.x, s = cs.y;
                int ipp = p * (p + 1) / 2 + p;
                int iqq = q * (q + 1) / 2 + q;
                int ipq = q * (q + 1) / 2 + p;
                float mpp = A[ipp], mqq = A[iqq], mpq = A[ipq];
                A[ipp] = c * c * mpp + 2.0f * c * s * mpq + s * s * mqq;
                A[iqq] = s * s * mpp - 2.0f * c * s * mpq + c * c * mqq;
                A[ipq] = c * s * (mqq - mpp) + (c * c - s * s) * mpq;
                c_arr[tid] = c; s_arr[tid] = s;
                p_arr[tid] = p; q_arr[tid] = q;
            }
            __syncthreads();
            for (int k = tid; k < 8128; k += 1024) {
                unsigned short ab = dtab[k];
                int aa = ab & 255, bb = ab >> 8;
                int p1 = p_arr[aa], q1 = q_arr[aa];
                int p2 = p_arr[bb], q2 = q_arr[bb];
                float ca = c_arr[aa], sa = s_arr[aa];
                float cb = c_arr[bb], sb = s_arr[bb];
                int i00 = pk(p1, p2), i01 = pk(p1, q2), i10 = pk(q1, p2), i11 = pk(q1, q2);
                float x00 = A[i00], x01 = A[i01], x10 = A[i10], x11 = A[i11];
                float y00 = ca * x00 + sa * x10, y10 = -sa * x00 + ca * x10;
                float y01 = ca * x01 + sa * x11, y11 = -sa * x01 + ca * x11;
                A[i00] = cb * y00 + sb * y01; A[i01] = -sb * y00 + cb * y01;
                A[i10] = cb * y10 + sb * y11; A[i11] = -sb * y10 + cb * y11;
            }
            __syncthreads();
        }
    }

    // ---- write triu-flattened output with sqrt(2) off-diagonal scaling
    float* flatb = flat + (size_t)b * 32896;
    const float SQ2 = 1.41421356237309515f;
    for (int e = tid; e < 32896; e += 1024) {
        int rr = (int)((sqrtf(8.0f * e + 1.0f) - 1.0f) * 0.5f);
        while (rr * (rr + 1) / 2 > e) --rr;
        while ((rr + 1) * (rr + 2) / 2 <= e) ++rr;
        int cc = e - rr * (rr + 1) / 2;
        int i = cc, j = rr;  // upper-tri coords, i <= j
        int fidx = i * 256 - i * (i - 1) / 2 + (j - i);
        flatb[fidx] = A[e] * ((i == j) ? 1.0f : SQ2);
    }
}

// ---------------- k5: MLP layer-1 partial GEMM: partial[jt*32+ec][pair] over e-chunk
__global__ __launch_bounds__(256) void k_mlp1(const float* __restrict__ flat,
                                              const float* __restrict__ W1,
                                              float* __restrict__ partial) {
    __shared__ float Fl[32][65];
    __shared__ float Wl[32][65];
    int ec = blockIdx.x, jt = blockIdx.y;
    int tid = threadIdx.x;
    int e0 = ec * 1028;  // 32 * 1028 = 32896 exactly
    float acc[4] = {};
    for (int ch = 0; ch < 1028; ch += 64) {
        __syncthreads();
        for (int idx = tid; idx < 2048; idx += 256) {
            int row = idx >> 6, col = idx & 63;
            int e = ch + col;
            float fv = 0.0f, wv = 0.0f;
            if (e < 1028) {
                fv = flat[(size_t)row * 32896 + e0 + e];
                wv = W1[(size_t)(jt * 32 + row) * 32896 + e0 + e];
            }
            Fl[row][col] = fv; Wl[row][col] = wv;
        }
        __syncthreads();
#pragma unroll 4
        for (int ee = 0; ee < 64; ++ee) {
#pragma unroll
            for (int pp = 0; pp < 4; ++pp) {
                int pair = tid + pp * 256;
                acc[pp] += Wl[pair >> 5][ee] * Fl[pair & 31][ee];
            }
        }
    }
    for (int pp = 0; pp < 4; ++pp)
        partial[((size_t)(jt * 32 + ec) << 10) + tid + pp * 256] = acc[pp];
}

// ---------------- k6: reduce partials + bias + relu -> h[32][256]
__global__ __launch_bounds__(1024) void k_mlp1red(const float* __restrict__ partial,
                                                  const float* __restrict__ b1,
                                                  float* __restrict__ h) {
    int jt = blockIdx.x, tid = threadIdx.x;
    float acc = 0.0f;
    for (int ec = 0; ec < 32; ++ec) acc += partial[((size_t)(jt * 32 + ec) << 10) + tid];
    int j = jt * 32 + (tid >> 5), bI = tid & 31;
    h[bI * 256 + j] = fmaxf(acc + b1[j], 0.0f);
}

// ---------------- k7: final classifier
__global__ __launch_bounds__(128) void k_mlp2(const float* __restrict__ h,
                                              const float* __restrict__ W2,
                                              const float* __restrict__ b2,
                                              float* __restrict__ out) {
    int tid = threadIdx.x;
    if (tid >= 96) return;
    int bI = tid / 3, cls = tid % 3;
    double acc = (double)b2[cls];
    for (int j = 0; j < 256; ++j) acc += (double)h[bI * 256 + j] * (double)W2[cls * 256 + j];
    out[tid] = (float)acc;
}

extern "C" void kernel_launch(void* const* d_in, const int* in_sizes, int n_in,
                              void* d_out, int out_size, void* d_ws, size_t ws_size,
                              hipStream_t stream) {
    const float* x  = (const float*)d_in[0];
    const float* Wr = (const float*)d_in[1];
    const float* W1 = (const float*)d_in[2];
    const float* b1 = (const float*)d_in[3];
    const float* W2 = (const float*)d_in[4];
    const float* b2 = (const float*)d_in[5];
    float* out = (float*)d_out;
    char* ws = (char*)d_ws;
    if (ws_size < (size_t)WS_REQUIRED) return;  // fail cleanly if scratch too small

    float*  P    = (float*)(ws + P_OFF);
    float*  mean = (float*)(ws + MEAN_OFF);
    float2* rlog = (float2*)(ws + RLOG_OFF);
    float*  f    = (float*)(ws + F_OFF);
    float*  flat = (float*)(ws + FLAT_OFF);
    float*  cov  = (float*)(ws + COV_OFF);
    float*  part = (float*)(ws + PART_OFF);
    float*  h    = (float*)(ws + H_OFF);
    float*  rmax = (float*)(ws + RMAX_OFF);

    // Jacobi kernel needs 150,920 B of dynamic LDS (opt-in above 64 KB)
    hipFuncSetAttribute((const void*)k_jacobi,
                        hipFuncAttributeMaxDynamicSharedMemorySize, 150920);

    k_pool<<<dim3(2048, 32), 256, 0, stream>>>(x, P);
    k_gemm_red<<<dim3(5, 8, 32), 256, 0, stream>>>(P, Wr, f);
    k_mean<<<2048, 256, 0, stream>>>(f, mean);
    k_cov<<<dim3(32, 36), 256, 0, stream>>>(f, mean, cov);
    k_jacobi<<<32, 1024, 150920, stream>>>(cov, rlog, rmax, flat);
    k_mlp1<<<dim3(32, 8), 256, 0, stream>>>(flat, W1, part);
    k_mlp1red<<<8, 1024, 0, stream>>>(part, b1, h);
    k_mlp2<<<1, 128, 0, stream>>>(h, W2, b2, out);
}

// Round 2
// 12699.472 us; speedup vs baseline: 1.7223x; 1.7223x over previous
//
#include <hip/hip_runtime.h>
#include <math.h>

// OSPNet: pool(2x2) -> 1x1 conv -> spatial covariance -> eigh -> log(clamp(w,1e-4))
//         -> V diag(logw) V^T -> triu flatten (*sqrt2 offdiag) -> MLP -> [32,3]
//
// R2: block Jacobi (16 blocks of 16; 32x32 subproblems) with forward V-accumulation.
//     105 serial rounds (vs 5100 scalar), updates spread over all 256 CUs as dense
//     32^3 GEMMs. log(cov) = V diag(log lambda) V^T as one batched GEMM at the end.

#define SWEEPS 7          // outer block-Jacobi sweeps (15 rounds each)
#define NROUNDS (SWEEPS * 15)

// ---- workspace layout (bytes) ----
// P [0, 79691776) dead after k_gemm_red; A/V/U/logw overlay its corpse.
#define P_OFF     0
#define A_OFF     0            // 32*256*256*4 = 8388608
#define V_OFF     8388608      // 8388608
#define U_OFF     16777216     // 32*8*1024*4 = 1048576
#define LOGW_OFF  17825792     // 32*256*4 = 32768
#define MEAN_OFF  79691776     // 32768
#define F_OFF     83558400     // 9961472 (dead after k_cov)
#define FLAT_OFF  83558400     // 4210688 (overlays f)
#define PART_OFF  93519872     // 1048576
#define H_OFF     94568448     // 32768
#define WS_REQUIRED 94601216

// round-robin tournaments
__device__ __forceinline__ void pair16(int r, int t, int& p, int& q) {
    if (t == 0) { p = 0; q = 1 + r; return; }
    int u = r + t; if (u >= 15) u -= 15;
    int v = r - t; if (v < 0) v += 15;
    p = 1 + u; q = 1 + v;
    if (p > q) { int w = p; p = q; q = w; }
}
__device__ __forceinline__ void pair32(int rr, int t, int& p, int& q) {
    if (t == 0) { p = 0; q = 1 + rr; return; }
    int u = rr + t; if (u >= 31) u -= 31;
    int v = rr - t; if (v < 0) v += 31;
    p = 1 + u; q = 1 + v;
    if (p > q) { int w = p; p = q; q = w; }
}

// ---------------- k1: 2x2 average pool
__global__ __launch_bounds__(256) void k_pool(const float* __restrict__ x, float* __restrict__ P) {
    int c = blockIdx.x, b = blockIdx.y;
    const float* xs = x + (size_t)(b * 2048 + c) * 1156;
    float* ps = P + (size_t)(b * 2048 + c) * 304;
    for (int n = threadIdx.x; n < 289; n += 256) {
        int i = n / 17, j = n % 17;
        int base = (2 * i) * 34 + 2 * j;
        ps[n] = 0.25f * (xs[base] + xs[base + 1] + xs[base + 34] + xs[base + 35]);
    }
}

// ---------------- k2: channel reduction GEMM
__global__ __launch_bounds__(256) void k_gemm_red(const float* __restrict__ P,
                                                  const float* __restrict__ Wr,
                                                  float* __restrict__ f) {
    __shared__ float Wt[32][33];
    __shared__ float Pt[32][64];
    int nt = blockIdx.x, dt = blockIdx.y, b = blockIdx.z;
    int n0 = nt * 64, d0 = dt * 32;
    int tid = threadIdx.x;
    int ty = tid >> 4, tx = tid & 15;
    float acc[2][4] = {};
    for (int c0 = 0; c0 < 2048; c0 += 32) {
        __syncthreads();
        for (int idx = tid; idx < 32 * 32; idx += 256) {
            int r = idx >> 5, cc = idx & 31;
            Wt[r][cc] = Wr[(size_t)(d0 + r) * 2048 + c0 + cc];
        }
        for (int idx = tid; idx < 32 * 64; idx += 256) {
            int r = idx >> 6, cc = idx & 63;
            int n = n0 + cc;
            Pt[r][cc] = (n < 289) ? P[(size_t)(b * 2048 + c0 + r) * 304 + n] : 0.0f;
        }
        __syncthreads();
#pragma unroll
        for (int kk = 0; kk < 32; ++kk) {
            float a0 = Wt[ty * 2 + 0][kk], a1 = Wt[ty * 2 + 1][kk];
            float p0 = Pt[kk][tx * 4 + 0], p1 = Pt[kk][tx * 4 + 1];
            float p2 = Pt[kk][tx * 4 + 2], p3 = Pt[kk][tx * 4 + 3];
            acc[0][0] += a0 * p0; acc[0][1] += a0 * p1; acc[0][2] += a0 * p2; acc[0][3] += a0 * p3;
            acc[1][0] += a1 * p0; acc[1][1] += a1 * p1; acc[1][2] += a1 * p2; acc[1][3] += a1 * p3;
        }
    }
    for (int ii = 0; ii < 2; ++ii)
        for (int jj = 0; jj < 4; ++jj) {
            int d = d0 + ty * 2 + ii, n = n0 + tx * 4 + jj;
            if (n < 289) f[(size_t)(b * 256 + d) * 304 + n] = acc[ii][jj];
        }
}

// ---------------- k3a: per-(b,d) spatial mean (fp64 accumulate)
__global__ __launch_bounds__(256) void k_mean(const float* __restrict__ f, float* __restrict__ mean) {
    int row = blockIdx.x * 4 + (threadIdx.x >> 6);
    int lane = threadIdx.x & 63;
    const float* fr = f + (size_t)row * 304;
    double s = 0.0;
    for (int n = lane; n < 289; n += 64) s += (double)fr[n];
    for (int off = 32; off; off >>= 1) s += __shfl_down(s, off);
    if (lane == 0) mean[row] = (float)(s / 289.0);
}

// ---------------- k3b: covariance (fp64 accumulate), writes FULL square A
__global__ __launch_bounds__(256) void k_cov(const float* __restrict__ f,
                                             const float* __restrict__ mean,
                                             float* __restrict__ A) {
    __shared__ float Fi[32][33];
    __shared__ float Fj[32][33];
    int b = blockIdx.x, tp = blockIdx.y;
    int ti = (int)((sqrtf(8.0f * tp + 1.0f) - 1.0f) * 0.5f);
    while (ti * (ti + 1) / 2 > tp) --ti;
    while ((ti + 1) * (ti + 2) / 2 <= tp) ++ti;
    int tj = tp - ti * (ti + 1) / 2;
    int tid = threadIdx.x;
    int tyy = tid >> 4, txx = tid & 15;
    bool diag = (ti == tj);
    double acc[2][2] = {};
    for (int nc = 0; nc < 289; nc += 32) {
        __syncthreads();
        for (int idx = tid; idx < 32 * 32; idx += 256) {
            int r = idx >> 5, k = idx & 31;
            int n = nc + k;
            int d1 = ti * 32 + r;
            Fi[r][k] = (n < 289) ? f[(size_t)(b * 256 + d1) * 304 + n] - mean[b * 256 + d1] : 0.0f;
            if (!diag) {
                int d2 = tj * 32 + r;
                Fj[r][k] = (n < 289) ? f[(size_t)(b * 256 + d2) * 304 + n] - mean[b * 256 + d2] : 0.0f;
            }
        }
        __syncthreads();
        const float(*FJ)[33] = diag ? Fi : Fj;
#pragma unroll 8
        for (int kk = 0; kk < 32; ++kk) {
            float a0 = Fi[tyy * 2 + 0][kk], a1 = Fi[tyy * 2 + 1][kk];
            float c0 = FJ[txx * 2 + 0][kk], c1 = FJ[txx * 2 + 1][kk];
            acc[0][0] += (double)a0 * c0; acc[0][1] += (double)a0 * c1;
            acc[1][0] += (double)a1 * c0; acc[1][1] += (double)a1 * c1;
        }
    }
    for (int ii = 0; ii < 2; ++ii)
        for (int jj = 0; jj < 2; ++jj) {
            int i = ti * 32 + tyy * 2 + ii, j = tj * 32 + txx * 2 + jj;
            float v = (float)(acc[ii][jj] * (1.0 / 288.0));
            A[((size_t)b << 16) + i * 256 + j] = v;
            if (!diag) A[((size_t)b << 16) + j * 256 + i] = v;
        }
}

// ---------------- k_init_v: V = I
__global__ __launch_bounds__(256) void k_init_v(float* __restrict__ V) {
    int i = blockIdx.x, b = blockIdx.y, j = threadIdx.x;
    V[((size_t)b << 16) + i * 256 + j] = (i == j) ? 1.0f : 0.0f;
}

// ---------------- k_inner: solve 8 x 32 subproblems (32x32 scalar Jacobi), emit U
__global__ __launch_bounds__(256) void k_inner(const float* __restrict__ A,
                                               float* __restrict__ Ubuf, int r) {
    __shared__ float S[32][33], UU[32][33];
    __shared__ float cbuf[16], sbuf[16];
    __shared__ int pbuf[16], qbuf[16];
    __shared__ float rednorm[8];
    int g = blockIdx.x, b = blockIdx.y;
    int tid = threadIdx.x;
    int bp, bq; pair16(r, g, bp, bq);
    const float* Ab = A + ((size_t)b << 16);
    for (int e = tid; e < 1024; e += 256) {
        int i = e >> 5, j = e & 31;
        int ri = (i < 16) ? bp * 16 + i : bq * 16 + i - 16;
        int rj = (j < 16) ? bp * 16 + j : bq * 16 + j - 16;
        S[i][j] = Ab[ri * 256 + rj];
        UU[i][j] = (i == j) ? 1.0f : 0.0f;
    }
    __syncthreads();
    for (int sw = 0; sw < 6; ++sw) {
        // off-diagonal norm -> adaptive early exit
        float off = 0.0f, dia = 0.0f;
        for (int e = tid; e < 1024; e += 256) {
            int i = e >> 5, j = e & 31; float v = S[i][j];
            if (i == j) dia += v * v; else off += v * v;
        }
        for (int o = 32; o; o >>= 1) { off += __shfl_down(off, o); dia += __shfl_down(dia, o); }
        if ((tid & 63) == 0) { rednorm[tid >> 6] = off; rednorm[4 + (tid >> 6)] = dia; }
        __syncthreads();
        off = rednorm[0] + rednorm[1] + rednorm[2] + rednorm[3];
        dia = rednorm[4] + rednorm[5] + rednorm[6] + rednorm[7];
        __syncthreads();
        if (off <= 1e-13f * fmaxf(dia, 1e-30f)) break;
        for (int rr = 0; rr < 31; ++rr) {
            if (tid < 16) {
                int p, q; pair32(rr, tid, p, q);
                float app = S[p][p], aqq = S[q][q], apq = S[p][q];
                float c = 1.0f, s = 0.0f;
                if (apq * apq > 1e-36f) {
                    float tau = (aqq - app) / (2.0f * apq);
                    float t = 1.0f / (fabsf(tau) + sqrtf(1.0f + tau * tau));
                    if (tau < 0.0f) t = -t;
                    c = rsqrtf(1.0f + t * t); s = t * c;
                }
                cbuf[tid] = c; sbuf[tid] = s; pbuf[tid] = p; qbuf[tid] = q;
            }
            __syncthreads();
            {   // column pass on S and U (2 pairs per thread)
                int i = tid & 31, t0 = (tid >> 5) * 2;
#pragma unroll
                for (int m = 0; m < 2; ++m) {
                    int t = t0 + m;
                    int p = pbuf[t], q = qbuf[t];
                    float c = cbuf[t], s = sbuf[t];
                    float x = S[i][p], y = S[i][q];
                    S[i][p] = c * x - s * y; S[i][q] = s * x + c * y;
                    x = UU[i][p]; y = UU[i][q];
                    UU[i][p] = c * x - s * y; UU[i][q] = s * x + c * y;
                }
            }
            __syncthreads();
            {   // row pass on S
                int j = tid & 31, t0 = (tid >> 5) * 2;
#pragma unroll
                for (int m = 0; m < 2; ++m) {
                    int t = t0 + m;
                    int p = pbuf[t], q = qbuf[t];
                    float c = cbuf[t], s = sbuf[t];
                    float x = S[p][j], y = S[q][j];
                    S[p][j] = c * x - s * y; S[q][j] = s * x + c * y;
                }
            }
            __syncthreads();
        }
    }
    for (int e = tid; e < 1024; e += 256)
        Ubuf[(((size_t)b * 8 + g) << 10) + e] = UU[e >> 5][e & 31];
}

// ---------------- k_update: A_tile <- Uk^T A_tile Ul  (tasks 0..63), V <- V*Ul (64..127)
__global__ __launch_bounds__(64) void k_update(float* __restrict__ A, float* __restrict__ V,
                                               const float* __restrict__ Ubuf, int r) {
    __shared__ float U1[32][33], U2[32][33], TT[32][33];
    int task = blockIdx.x, b = blockIdx.y;
    int l = threadIdx.x;
    int lr = l >> 3, lc = l & 7;
    int a0 = lr * 4, c0 = lc * 4;
    if (task < 64) {
        int gk = task >> 3, gl = task & 7;
        int pk, qk, pl, ql;
        pair16(r, gk, pk, qk); pair16(r, gl, pl, ql);
        const float* Uk = Ubuf + (((size_t)b * 8 + gk) << 10);
        const float* Ul = Ubuf + (((size_t)b * 8 + gl) << 10);
        float* Ab = A + ((size_t)b << 16);
        for (int e = l; e < 1024; e += 64) {
            int i = e >> 5, j = e & 31;
            U1[i][j] = Uk[e];
            U2[i][j] = Ul[e];
            int ri = (i < 16) ? pk * 16 + i : qk * 16 + i - 16;
            int rj = (j < 16) ? pl * 16 + j : ql * 16 + j - 16;
            TT[i][j] = Ab[ri * 256 + rj];
        }
        __syncthreads();
        float acc[4][4] = {};
#pragma unroll 4
        for (int k = 0; k < 32; ++k) {
            float u0 = U1[k][a0], u1 = U1[k][a0 + 1], u2 = U1[k][a0 + 2], u3 = U1[k][a0 + 3];
            float t0 = TT[k][c0], t1 = TT[k][c0 + 1], t2 = TT[k][c0 + 2], t3 = TT[k][c0 + 3];
            acc[0][0] += u0 * t0; acc[0][1] += u0 * t1; acc[0][2] += u0 * t2; acc[0][3] += u0 * t3;
            acc[1][0] += u1 * t0; acc[1][1] += u1 * t1; acc[1][2] += u1 * t2; acc[1][3] += u1 * t3;
            acc[2][0] += u2 * t0; acc[2][1] += u2 * t1; acc[2][2] += u2 * t2; acc[2][3] += u2 * t3;
            acc[3][0] += u3 * t0; acc[3][1] += u3 * t1; acc[3][2] += u3 * t2; acc[3][3] += u3 * t3;
        }
        __syncthreads();
#pragma unroll
        for (int i = 0; i < 4; ++i)
#pragma unroll
            for (int j = 0; j < 4; ++j) TT[a0 + i][c0 + j] = acc[i][j];
        __syncthreads();
        float acc2[4][4] = {};
#pragma unroll 4
        for (int k = 0; k < 32; ++k) {
            float w0 = TT[a0][k], w1 = TT[a0 + 1][k], w2 = TT[a0 + 2][k], w3 = TT[a0 + 3][k];
            float u0 = U2[k][c0], u1 = U2[k][c0 + 1], u2 = U2[k][c0 + 2], u3 = U2[k][c0 + 3];
            acc2[0][0] += w0 * u0; acc2[0][1] += w0 * u1; acc2[0][2] += w0 * u2; acc2[0][3] += w0 * u3;
            acc2[1][0] += w1 * u0; acc2[1][1] += w1 * u1; acc2[1][2] += w1 * u2; acc2[1][3] += w1 * u3;
            acc2[2][0] += w2 * u0; acc2[2][1] += w2 * u1; acc2[2][2] += w2 * u2; acc2[2][3] += w2 * u3;
            acc2[3][0] += w3 * u0; acc2[3][1] += w3 * u1; acc2[3][2] += w3 * u2; acc2[3][3] += w3 * u3;
        }
#pragma unroll
        for (int i = 0; i < 4; ++i) {
            int ga = a0 + i; int ri = (ga < 16) ? pk * 16 + ga : qk * 16 + ga - 16;
#pragma unroll
            for (int j = 0; j < 4; ++j) {
                int gc = c0 + j; int rj = (gc < 16) ? pl * 16 + gc : ql * 16 + gc - 16;
                Ab[ri * 256 + rj] = acc2[i][j];
            }
        }
    } else {
        int t2 = task - 64;
        int rb = t2 >> 3, gl = t2 & 7;
        int pl, ql; pair16(r, gl, pl, ql);
        const float* Ul = Ubuf + (((size_t)b * 8 + gl) << 10);
        float* Vb = V + ((size_t)b << 16);
        for (int e = l; e < 1024; e += 64) {
            int i = e >> 5, j = e & 31;
            U2[i][j] = Ul[e];
            int rj = (j < 16) ? pl * 16 + j : ql * 16 + j - 16;
            TT[i][j] = Vb[(rb * 32 + i) * 256 + rj];
        }
        __syncthreads();
        float acc2[4][4] = {};
#pragma unroll 4
        for (int k = 0; k < 32; ++k) {
            float w0 = TT[a0][k], w1 = TT[a0 + 1][k], w2 = TT[a0 + 2][k], w3 = TT[a0 + 3][k];
            float u0 = U2[k][c0], u1 = U2[k][c0 + 1], u2 = U2[k][c0 + 2], u3 = U2[k][c0 + 3];
            acc2[0][0] += w0 * u0; acc2[0][1] += w0 * u1; acc2[0][2] += w0 * u2; acc2[0][3] += w0 * u3;
            acc2[1][0] += w1 * u0; acc2[1][1] += w1 * u1; acc2[1][2] += w1 * u2; acc2[1][3] += w1 * u3;
            acc2[2][0] += w2 * u0; acc2[2][1] += w2 * u1; acc2[2][2] += w2 * u2; acc2[2][3] += w2 * u3;
            acc2[3][0] += w3 * u0; acc2[3][1] += w3 * u1; acc2[3][2] += w3 * u2; acc2[3][3] += w3 * u3;
        }
#pragma unroll
        for (int i = 0; i < 4; ++i)
#pragma unroll
            for (int j = 0; j < 4; ++j) {
                int gc = c0 + j; int rj = (gc < 16) ? pl * 16 + gc : ql * 16 + gc - 16;
                Vb[(rb * 32 + a0 + i) * 256 + rj] = acc2[i][j];
            }
    }
}

// ---------------- k_logw: logw = log(clamp(diag(A), 1e-4))
__global__ __launch_bounds__(256) void k_logw(const float* __restrict__ A, float* __restrict__ logw) {
    int b = blockIdx.x, k = threadIdx.x;
    logw[b * 256 + k] = logf(fmaxf(A[((size_t)b << 16) + k * 257], 1e-4f));
}

// ---------------- k_vlogv: L = V diag(logw) V^T, fused triu flatten (*sqrt2 offdiag)
__global__ __launch_bounds__(256) void k_vlogv(const float* __restrict__ V,
                                               const float* __restrict__ logw,
                                               float* __restrict__ flat) {
    __shared__ float Vi[32][33], Vjw[32][33];
    int t = blockIdx.x, b = blockIdx.y;
    int ti = 0;
    while (t >= 8 - ti) { t -= 8 - ti; ++ti; }
    int tj = ti + t;
    int tid = threadIdx.x;
    int ty = tid >> 4, tx = tid & 15;
    const float* Vb = V + ((size_t)b << 16);
    const float* wb = logw + b * 256;
    float acc[2][2] = {};
    for (int kc = 0; kc < 8; ++kc) {
        __syncthreads();
        for (int e = tid; e < 1024; e += 256) {
            int rr = e >> 5, cc = e & 31;
            Vi[rr][cc] = Vb[(ti * 32 + rr) * 256 + kc * 32 + cc];
            Vjw[rr][cc] = Vb[(tj * 32 + rr) * 256 + kc * 32 + cc] * wb[kc * 32 + cc];
        }
        __syncthreads();
#pragma unroll 8
        for (int k = 0; k < 32; ++k) {
            float a0 = Vi[ty * 2][k], a1 = Vi[ty * 2 + 1][k];
            float b0 = Vjw[tx * 2][k], b1 = Vjw[tx * 2 + 1][k];
            acc[0][0] += a0 * b0; acc[0][1] += a0 * b1;
            acc[1][0] += a1 * b0; acc[1][1] += a1 * b1;
        }
    }
    const float SQ2 = 1.41421356237309515f;
    float* flatb = flat + (size_t)b * 32896;
#pragma unroll
    for (int ii = 0; ii < 2; ++ii)
#pragma unroll
        for (int jj = 0; jj < 2; ++jj) {
            int gi = ti * 32 + ty * 2 + ii, gj = tj * 32 + tx * 2 + jj;
            if (gi <= gj) {
                int fidx = gi * 256 - gi * (gi - 1) / 2 + (gj - gi);
                flatb[fidx] = acc[ii][jj] * ((gi == gj) ? 1.0f : SQ2);
            }
        }
}

// ---------------- k5: MLP layer-1 partial GEMM
__global__ __launch_bounds__(256) void k_mlp1(const float* __restrict__ flat,
                                              const float* __restrict__ W1,
                                              float* __restrict__ partial) {
    __shared__ float Fl[32][65];
    __shared__ float Wl[32][65];
    int ec = blockIdx.x, jt = blockIdx.y;
    int tid = threadIdx.x;
    int e0 = ec * 1028;
    float acc[4] = {};
    for (int ch = 0; ch < 1028; ch += 64) {
        __syncthreads();
        for (int idx = tid; idx < 2048; idx += 256) {
            int row = idx >> 6, col = idx & 63;
            int e = ch + col;
            float fv = 0.0f, wv = 0.0f;
            if (e < 1028) {
                fv = flat[(size_t)row * 32896 + e0 + e];
                wv = W1[(size_t)(jt * 32 + row) * 32896 + e0 + e];
            }
            Fl[row][col] = fv; Wl[row][col] = wv;
        }
        __syncthreads();
#pragma unroll 4
        for (int ee = 0; ee < 64; ++ee) {
#pragma unroll
            for (int pp = 0; pp < 4; ++pp) {
                int pair = tid + pp * 256;
                acc[pp] += Wl[pair >> 5][ee] * Fl[pair & 31][ee];
            }
        }
    }
    for (int pp = 0; pp < 4; ++pp)
        partial[((size_t)(jt * 32 + ec) << 10) + tid + pp * 256] = acc[pp];
}

// ---------------- k6: reduce partials + bias + relu
__global__ __launch_bounds__(1024) void k_mlp1red(const float* __restrict__ partial,
                                                  const float* __restrict__ b1,
                                                  float* __restrict__ h) {
    int jt = blockIdx.x, tid = threadIdx.x;
    float acc = 0.0f;
    for (int ec = 0; ec < 32; ++ec) acc += partial[((size_t)(jt * 32 + ec) << 10) + tid];
    int j = jt * 32 + (tid >> 5), bI = tid & 31;
    h[bI * 256 + j] = fmaxf(acc + b1[j], 0.0f);
}

// ---------------- k7: final classifier
__global__ __launch_bounds__(128) void k_mlp2(const float* __restrict__ h,
                                              const float* __restrict__ W2,
                                              const float* __restrict__ b2,
                                              float* __restrict__ out) {
    int tid = threadIdx.x;
    if (tid >= 96) return;
    int bI = tid / 3, cls = tid % 3;
    double acc = (double)b2[cls];
    for (int j = 0; j < 256; ++j) acc += (double)h[bI * 256 + j] * (double)W2[cls * 256 + j];
    out[tid] = (float)acc;
}

extern "C" void kernel_launch(void* const* d_in, const int* in_sizes, int n_in,
                              void* d_out, int out_size, void* d_ws, size_t ws_size,
                              hipStream_t stream) {
    const float* x  = (const float*)d_in[0];
    const float* Wr = (const float*)d_in[1];
    const float* W1 = (const float*)d_in[2];
    const float* b1 = (const float*)d_in[3];
    const float* W2 = (const float*)d_in[4];
    const float* b2 = (const float*)d_in[5];
    float* out = (float*)d_out;
    char* ws = (char*)d_ws;
    if (ws_size < (size_t)WS_REQUIRED) return;

    float* P    = (float*)(ws + P_OFF);
    float* A    = (float*)(ws + A_OFF);
    float* V    = (float*)(ws + V_OFF);
    float* Ubuf = (float*)(ws + U_OFF);
    float* logw = (float*)(ws + LOGW_OFF);
    float* mean = (float*)(ws + MEAN_OFF);
    float* f    = (float*)(ws + F_OFF);
    float* flat = (float*)(ws + FLAT_OFF);
    float* part = (float*)(ws + PART_OFF);
    float* h    = (float*)(ws + H_OFF);

    k_pool<<<dim3(2048, 32), 256, 0, stream>>>(x, P);
    k_gemm_red<<<dim3(5, 8, 32), 256, 0, stream>>>(P, Wr, f);
    k_mean<<<2048, 256, 0, stream>>>(f, mean);
    k_cov<<<dim3(32, 36), 256, 0, stream>>>(f, mean, A);
    k_init_v<<<dim3(256, 32), 256, 0, stream>>>(V);
    for (int r = 0; r < NROUNDS; ++r) {
        int rr = r % 15;
        k_inner<<<dim3(8, 32), 256, 0, stream>>>(A, Ubuf, rr);
        k_update<<<dim3(128, 32), 64, 0, stream>>>(A, V, Ubuf, rr);
    }
    k_logw<<<32, 256, 0, stream>>>(A, logw);
    k_vlogv<<<dim3(36, 32), 256, 0, stream>>>(V, logw, flat);
    k_mlp1<<<dim3(32, 8), 256, 0, stream>>>(flat, W1, part);
    k_mlp1red<<<8, 1024, 0, stream>>>(part, b1, h);
    k_mlp2<<<1, 128, 0, stream>>>(h, W2, b2, out);
}